// Round 3
// baseline (324.861 us; speedup 1.0000x reference)
//
#include <hip/hip_runtime.h>
#include <cstdint>
#include <cmath>

typedef __bf16 bf16x8 __attribute__((ext_vector_type(8)));
typedef float  f32x4  __attribute__((ext_vector_type(4)));

#define DEVI __device__ __forceinline__

#define SEQ 4096
#define NH 8
#define NKV 4
#define HD 256
#define WIN 1024

DEVI void gload16(const void* g, void* l) {
  __builtin_amdgcn_global_load_lds((const __attribute__((address_space(1))) void*)g,
                                   (__attribute__((address_space(3))) void*)l,
                                   16, 0, 0);
}

DEVI bf16x8 ld8f(const float* p) {
  const f32x4 a = *(const f32x4*)p;
  const f32x4 b = *(const f32x4*)(p + 4);
  bf16x8 r;
#pragma unroll
  for (int j = 0; j < 4; ++j) { r[j] = (__bf16)a[j]; r[4 + j] = (__bf16)b[j]; }
  return r;
}

DEVI void st1(float* p, float v)  { *p = v; }
DEVI void st1(__bf16* p, float v) { *p = (__bf16)v; }

// raw barrier (no vmcnt(0) drain, unlike __syncthreads) + compiler memory fence
DEVI void barx() {
  asm volatile("" ::: "memory");
  __builtin_amdgcn_s_barrier();
  asm volatile("" ::: "memory");
}

// ---------------------------------------------------------------------------
// fp32 -> bf16 conversion. Wq/Wk/Wv concatenated into one 4096x2048 buffer.
// ---------------------------------------------------------------------------
__global__ __launch_bounds__(256)
void cvt_all(const float* __restrict__ x,  const float* __restrict__ wq,
             const float* __restrict__ wk, const float* __restrict__ wv,
             const float* __restrict__ wo,
             __bf16* __restrict__ xb, __bf16* __restrict__ wqkvb,
             __bf16* __restrict__ wob) {
  const size_t g = (size_t)blockIdx.x * 256 + threadIdx.x;
  const float* src; __bf16* dst; size_t off;
  if      (g < 1048576) { src = x;  dst = xb;               off = g; }
  else if (g < 1572864) { src = wq; dst = wqkvb;            off = g - 1048576; }
  else if (g < 1835008) { src = wk; dst = wqkvb + 4194304;  off = g - 1572864; }
  else if (g < 2097152) { src = wv; dst = wqkvb + 6291456;  off = g - 1835008; }
  else                  { src = wo; dst = wob;              off = g - 2097152; }
  *(bf16x8*)(dst + off * 8) = ld8f(src + off * 8);
}

// ---------------------------------------------------------------------------
// GEMM: C[M][N] = A[M][K] * B[N][K]^T, bf16 in, f32 acc.
// Round 3: m201-style 4-phase fine interleave per K-tile (BK=64, halves h0/h1):
//   phase = { ds_reads (this quadrant) ; stage 1 unit ; [vmcnt gate p1/p3] ;
//             raw barrier ; setprio(1) 16 MFMA setprio(0) }.
//   Reads of phase p+1 issue under phase p's MFMA execution.
//   Stage schedule: p0:A.h1(kt+1)  p1:B.h1(kt+1)  p2:A.h0(kt+2)  p3:B.h0(kt+2)
//   — each unit's target slot was last read ≥1 barrier earlier (WAR-safe):
//     slot(A.h0,buf kt&1) last read p1(kt), overwritten p2(kt) [kt+2 same buf];
//     slot(A.h1,buf (kt+1)&1) last read p3(kt-1)? -> staged p0(kt). etc.
//   vmcnt(VMC=2*AI+4) at p1 protects h1(kt) reads (p2/p3); at p3 protects
//   h0(kt+1) reads (p0/p1 next tile). Lookahead ≈ 6 phases. Prologue issues
//   6 units in steady-state order so the same constant is exact; tail units
//   are clamped dummy re-issues (uniform counts, never read).
// ---------------------------------------------------------------------------
template <int BM, typename TC>
__global__ __launch_bounds__(512, 2)
void gemm256(const __bf16* __restrict__ A, const __bf16* __restrict__ B,
             TC* __restrict__ C, int N, int K) {
  constexpr int AI    = BM / 128;        // gload_lds instrs per A unit
  constexpr int MF    = BM / 32;         // M fragments per wave (4 or 8)
  constexpr int MH    = MF / 2;          // M fragments per phase
  constexpr int AUNIT = BM * 64;         // bytes per A (buf,half) unit
  constexpr int ASZ   = 4 * AUNIT;       // whole A region
  constexpr int VMC   = 2 * AI + 4;      // counted vmcnt (8 or 6)
  __shared__ char lds[ASZ + 65536];      // + B region: 4 * 16384

  const int tid  = threadIdx.x;
  const int lane = tid & 63;
  const int wave = tid >> 6;
  const int l15  = lane & 15;
  const int l4   = lane >> 4;
  const int wm   = wave >> 2;            // 0..1
  const int wn   = wave & 3;             // 0..3

  constexpr int nTm = 4096 / BM;
  const int lin  = blockIdx.x;
  const int xcd  = lin & 7;
  const int kk   = lin >> 3;
  const int nTn  = N >> 8;
  const int rowT = kk % nTm;
  const int colT = xcd * (nTn >> 3) + kk / nTm;
  const int row0 = rowT * BM;
  const int col0 = colT << 8;

  // staging: linear LDS dest; source col16 pre-swizzled (involution, m173)
  const int srow = tid >> 2;
  const int scol = ((tid & 3) ^ ((tid >> 3) & 3)) << 3;
  const __bf16* Asrc = A + (size_t)(row0 + srow) * K + scol;
  const __bf16* Bsrc = B + (size_t)(col0 + srow) * K + scol;

  // read-side swizzled fragment offsets
  const int swz  = (l4 ^ ((l15 >> 1) & 3)) << 4;
  const int aoff = (wm * (BM / 2) + l15) * 64 + swz;
  const int boff = ((wn << 6) + l15) * 64 + swz;

  auto stA = [&](int kx, int h) {
    int k0 = kx << 6; if (k0 >= K) k0 = 0;      // tail: clamped dummy re-issue
    const __bf16* s = Asrc + k0 + (h << 5);
    char* d = lds + ((kx & 1) * 2 + h) * AUNIT + wave * 1024;
#pragma unroll
    for (int i = 0; i < AI; ++i)
      gload16(s + (size_t)(i << 7) * K, d + i * 8192);
  };
  auto stB = [&](int kx, int h) {
    int k0 = kx << 6; if (k0 >= K) k0 = 0;
    const __bf16* s = Bsrc + k0 + (h << 5);
    char* d = lds + ASZ + ((kx & 1) * 2 + h) * 16384 + wave * 1024;
#pragma unroll
    for (int i = 0; i < 2; ++i)
      gload16(s + (size_t)(i << 7) * K, d + i * 8192);
  };

  f32x4 acc[MF][4] = {};

  // prologue: steady-state unit order {A.h0(0),B.h0(0),A.h1(0),B.h1(0),A.h0(1),B.h0(1)}
  stA(0, 0); stB(0, 0); stA(0, 1); stB(0, 1); stA(1, 0); stB(1, 0);
  asm volatile("s_waitcnt vmcnt(%0)" :: "i"(VMC) : "memory");
  barx();

  const int NT = K >> 6;
  for (int kt = 0; kt < NT; ++kt) {
    const int bb = (kt & 1) * 2;
    bf16x8 bfr[4];
    bf16x8 af[MH];

    auto rd = [&](int h, int mg, bool readB) {
      const char* pa = lds + (bb + h) * AUNIT + aoff;
#pragma unroll
      for (int m = 0; m < MH; ++m)
        af[m] = *(const bf16x8*)(pa + ((mg * MH + m) << 10));
      if (readB) {
        const char* pb = lds + ASZ + (bb + h) * 16384 + boff;
#pragma unroll
        for (int n = 0; n < 4; ++n)
          bfr[n] = *(const bf16x8*)(pb + (n << 10));
      }
    };
    auto mm = [&](int mg) {
      barx();
      __builtin_amdgcn_s_setprio(1);
#pragma unroll
      for (int m = 0; m < MH; ++m)
#pragma unroll
        for (int n = 0; n < 4; ++n)
          acc[mg * MH + m][n] =
              __builtin_amdgcn_mfma_f32_16x16x32_bf16(af[m], bfr[n], acc[mg * MH + m][n], 0, 0, 0);
      __builtin_amdgcn_s_setprio(0);
    };

    // p0
    rd(0, 0, true);
    stA(kt + 1, 1);
    mm(0);
    // p1
    rd(0, 1, false);
    stB(kt + 1, 1);
    asm volatile("s_waitcnt vmcnt(%0)" :: "i"(VMC) : "memory");
    mm(1);
    // p2
    rd(1, 0, true);
    stA(kt + 2, 0);
    mm(0);
    // p3
    rd(1, 1, false);
    stB(kt + 2, 0);
    asm volatile("s_waitcnt vmcnt(%0)" :: "i"(VMC) : "memory");
    mm(1);
  }
  // no DMA in flight at exit
  asm volatile("s_waitcnt vmcnt(0)" ::: "memory");

  // C/D layout: col = lane&15, row = (lane>>4)*4 + reg   [m89/m91 verified]
#pragma unroll
  for (int mf = 0; mf < MF; ++mf) {
    const int rb = row0 + wm * (BM / 2) + (mf >> 2) * 64 + (mf & 3) * 16 + (l4 << 2);
#pragma unroll
    for (int reg = 0; reg < 4; ++reg) {
      TC* crow = C + (size_t)(rb + reg) * N + col0 + (wn << 6) + l15;
#pragma unroll
      for (int n = 0; n < 4; ++n) st1(crow + (n << 4), acc[mf][n][reg]);
    }
  }
}

// ---------------------------------------------------------------------------
// Merged: per-head RMSNorm+RoPE (blocks 0..12287) and V-transpose (12288+).
// ---------------------------------------------------------------------------
__global__ __launch_bounds__(256)
void norm_rope_tv(__bf16* __restrict__ qkv, __bf16* __restrict__ Vt,
                  const float* __restrict__ qw, const float* __restrict__ kw,
                  const int* __restrict__ pos) {
  if (blockIdx.x < 12288) {
    const int gw   = blockIdx.x * 4 + (threadIdx.x >> 6);
    const int lane = threadIdx.x & 63;
    __bf16* base; const float* w; int t;
    if (gw < SEQ * NH) {
      t = gw >> 3;
      base = qkv + (size_t)t * 4096 + (gw & 7) * HD;
      w = qw;
    } else {
      const int g = gw - SEQ * NH;
      t = g >> 2;
      base = qkv + (size_t)t * 4096 + 2048 + (g & 3) * HD;
      w = kw;
    }

    const int d0 = lane * 4;
    float v[4]; float ss = 0.f;
#pragma unroll
    for (int j = 0; j < 4; ++j) { v[j] = (float)base[d0 + j]; ss += v[j] * v[j]; }
#pragma unroll
    for (int off = 1; off < 64; off <<= 1) ss += __shfl_xor(ss, off);
    const float rms = rsqrtf(ss * (1.0f / 256.0f) + 1e-6f);
    const float p = (float)pos[t];

    float n[4];
#pragma unroll
    for (int j = 0; j < 4; ++j) n[j] = v[j] * rms * w[d0 + j];

    float outv[4];
#pragma unroll
    for (int e = 0; e < 4; e += 2) {
      const int i0 = d0 + e, i1 = i0 + 1;
      const float f0 = exp2f(-(float)(i0 & 127) * 0.103810253f);
      const float f1 = exp2f(-(float)(i1 & 127) * 0.103810253f);
      float s0, cc0, s1, cc1;
      sincosf(p * f0, &s0, &cc0);
      sincosf(p * f1, &s1, &cc1);
      outv[e]     = n[e] * cc0 - n[e + 1] * s0;
      outv[e + 1] = n[e + 1] * cc1 + n[e] * s1;
    }
#pragma unroll
    for (int j = 0; j < 4; ++j) base[d0 + j] = (__bf16)outv[j];
  } else {
    __shared__ __bf16 tile[64][72];
    const int b   = blockIdx.x - 12288;       // 0..1023
    const int tid = threadIdx.x;
    const int tb  = (b & 63) * 64;
    const int yy  = b >> 6;                   // 0..15
    const int kvh = yy >> 2;
    const int db  = (yy & 3) * 64;
#pragma unroll
    for (int i = 0; i < 2; ++i) {
      const int s = i * 256 + tid;
      const int r = s >> 3, c = (s & 7) * 8;
      bf16x8 val = *(const bf16x8*)(qkv + (size_t)(tb + r) * 4096 + 3072 + kvh * HD + db + c);
#pragma unroll
      for (int j = 0; j < 8; ++j) tile[r][c + j] = val[j];
    }
    __syncthreads();
#pragma unroll
    for (int i = 0; i < 2; ++i) {
      const int s = i * 256 + tid;
      const int r = s >> 3, c = (s & 7) * 8;
      bf16x8 outv;
#pragma unroll
      for (int j = 0; j < 8; ++j) outv[j] = tile[c + j][r];
      *(bf16x8*)(Vt + (size_t)(kvh * HD + db + r) * SEQ + tb + c) = outv;
    }
  }
}

// ---------------------------------------------------------------------------
// Sliding-window flash attention (unchanged from round 2: KVBLK=32 dbuf,
// counted vmcnt(8), T2 swizzle, head-per-XCD pinning).
// ---------------------------------------------------------------------------
__global__ __launch_bounds__(256, 2)
void attn_fwd(const __bf16* __restrict__ qkv, const __bf16* __restrict__ Vt,
              __bf16* __restrict__ Y) {
  __shared__ char klds[2][16384];      // [8 ks][32 key][32 dim] rows of 64B, swz
  __shared__ char vlds[2][16384];      // [256 dim][32 key] rows of 64B, swz
  __shared__ __bf16 Ps[4][16][40];     // per-wave P (padded rows)
  const int tid  = threadIdx.x;
  const int lane = tid & 63;
  const int wave = tid >> 6;
  const int l15  = lane & 15;
  const int l4   = lane >> 4;
  const int lin  = blockIdx.x;
  const int head = lin & 7;            // head-per-XCD pinning
  const int q0   = (lin >> 3) * 64;
  const int kvh  = head >> 1;
  const int qw   = q0 + wave * 16;

  // Q fragments: A[m=lane&15][k=(lane>>4)*8+j]; pre-scale 1/16 (exact pow2)
  bf16x8 qf[8];
  const __bf16* qrow = qkv + (size_t)(qw + l15) * 4096 + head * HD;
#pragma unroll
  for (int ks = 0; ks < 8; ++ks) {
    bf16x8 t = *(const bf16x8*)(qrow + ks * 32 + l4 * 8);
#pragma unroll
    for (int j = 0; j < 8; ++j) t[j] = (__bf16)((float)t[j] * 0.0625f);
    qf[ks] = t;
  }

  f32x4 o[16] = {};
  float l_run[4] = {0.f, 0.f, 0.f, 0.f};

  int lo = q0 - (WIN - 1); if (lo < 0) lo = 0;
  const int kt0 = lo >> 5;
  const int kt1 = (q0 + 63) >> 5;      // >= kt0+1 always (>=2 tiles)
  const int kbmax = kt1 << 5;

  const int skey = (tid >> 2) & 31;                 // K: key row
  const int sdim = tid >> 2;                        // V: dim row (+ i*64)
  const int sg   = (tid & 3) ^ ((tid >> 3) & 3);    // swizzled source col16
  const int sth  = tid >> 7;

  auto stK = [&](int kt, int b) {
    int kb = kt << 5; if (kb > kbmax) kb = kbmax;   // clamped dummy re-issue
    const __bf16* s = qkv + (size_t)(kb + skey) * 4096 + 2048 + kvh * HD
                          + sth * 32 + sg * 8;
    char* d = klds[b] + wave * 1024;
#pragma unroll
    for (int i = 0; i < 4; ++i)
      gload16(s + i * 64, d + i * 4096);
  };
  auto stV = [&](int kt, int b) {
    int kb = kt << 5; if (kb > kbmax) kb = kbmax;
    const __bf16* s = Vt + ((size_t)kvh * HD + sdim) * SEQ + kb + sg * 8;
    char* d = vlds[b] + wave * 1024;
#pragma unroll
    for (int i = 0; i < 4; ++i)
      gload16(s + (size_t)i * 64 * SEQ, d + i * 4096);
  };

  stK(kt0, 0);     stV(kt0, 0);
  stK(kt0 + 1, 1); stV(kt0 + 1, 1);

  const int rswz = (l4 ^ ((l15 >> 1) & 3)) << 4;

  for (int kt = kt0; kt <= kt1; ++kt) {
    const int p  = (kt - kt0) & 1;
    const int kb = kt << 5;
    asm volatile("s_waitcnt vmcnt(8)" ::: "memory");
    barx();

    // S = (Q/16) K^T   (32 keys: kn = 0..1)
    const char* kbase = klds[p];
    f32x4 s_acc[2] = {};
    __builtin_amdgcn_s_setprio(1);
#pragma unroll
    for (int kn = 0; kn < 2; ++kn) {
#pragma unroll
      for (int ks = 0; ks < 8; ++ks) {
        bf16x8 kf = *(const bf16x8*)(kbase + (ks * 32 + kn * 16 + l15) * 64 + rswz);
        s_acc[kn] = __builtin_amdgcn_mfma_f32_16x16x32_bf16(qf[ks], kf, s_acc[kn], 0, 0, 0);
      }
    }
    __builtin_amdgcn_s_setprio(0);

    // fixed-max softmax: p = exp(min(s,34)-34); masked -> 0
#pragma unroll
    for (int reg = 0; reg < 4; ++reg) {
      const int r  = l4 * 4 + reg;
      const int qg = qw + r;
      float ps = 0.f;
#pragma unroll
      for (int kn = 0; kn < 2; ++kn) {
        const int kg = kb + kn * 16 + l15;
        const bool ok = (kg <= qg) && (kg > qg - WIN);
        const float pv = ok ? __expf(fminf(s_acc[kn][reg], 34.f) - 34.f) : 0.f;
        ps += pv;
        Ps[wave][r][kn * 16 + l15] = (__bf16)pv;
      }
      l_run[reg] += ps;
    }

    // O += P V   (Ps per-wave; intra-wave LDS ordering needs no barrier)
    const char* vbase = vlds[p];
    bf16x8 pf = *(const bf16x8*)&Ps[wave][l15][l4 * 8];
    __builtin_amdgcn_s_setprio(1);
#pragma unroll
    for (int dn = 0; dn < 16; ++dn) {
      bf16x8 vf = *(const bf16x8*)(vbase + (dn * 16 + l15) * 64 + rswz);
      o[dn] = __builtin_amdgcn_mfma_f32_16x16x32_bf16(pf, vf, o[dn], 0, 0, 0);
    }
    __builtin_amdgcn_s_setprio(0);

    barx();
    stK(kt + 2, p);
    stV(kt + 2, p);
  }
  asm volatile("s_waitcnt vmcnt(0)" ::: "memory");

  // epilogue: reduce l across the 16 lanes sharing each row, then scale
#pragma unroll
  for (int reg = 0; reg < 4; ++reg) {
#pragma unroll
    for (int off = 1; off < 16; off <<= 1)
      l_run[reg] += __shfl_xor(l_run[reg], off);
    const float inv = 1.0f / l_run[reg];
    const int q = qw + l4 * 4 + reg;
    __bf16* yrow = Y + ((size_t)q * NH + head) * HD + l15;
#pragma unroll
    for (int dn = 0; dn < 16; ++dn)
      yrow[dn * 16] = (__bf16)(o[dn][reg] * inv);
  }
}

// ---------------------------------------------------------------------------
extern "C" void kernel_launch(void* const* d_in, const int* in_sizes, int n_in,
                              void* d_out, int out_size, void* d_ws, size_t ws_size,
                              hipStream_t stream) {
  (void)in_sizes; (void)n_in; (void)out_size; (void)ws_size;
  const float* x   = (const float*)d_in[0];
  const int*   pos = (const int*)d_in[1];
  const float* Wq  = (const float*)d_in[2];
  const float* Wk  = (const float*)d_in[3];
  const float* Wv  = (const float*)d_in[4];
  const float* Wo  = (const float*)d_in[5];
  const float* qw  = (const float*)d_in[6];
  const float* kw  = (const float*)d_in[7];
  float* out = (float*)d_out;

  char* ws = (char*)d_ws;
  const size_t MB = 1024 * 1024;
  __bf16* qkv_ws = (__bf16*)(ws);             // 32 MiB  [4096][4096]
  __bf16* vt_ws  = (__bf16*)(ws + 32 * MB);   //  8 MiB  [4][256][4096]
  __bf16* y_ws   = (__bf16*)(ws + 40 * MB);   // 16 MiB  [4096][2048]
  __bf16* xb     = (__bf16*)(ws + 56 * MB);   // 16 MiB
  __bf16* wqkvb  = (__bf16*)(ws + 72 * MB);   // 16 MiB  [4096][2048]
  __bf16* wob    = (__bf16*)(ws + 88 * MB);   //  8 MiB  (total 96 MiB)

  cvt_all<<<dim3(10240), dim3(256), 0, stream>>>(x, Wq, Wk, Wv, Wo, xb, wqkvb, wob);
  gemm256<256, __bf16><<<dim3(256), dim3(512), 0, stream>>>(xb, wqkvb, qkv_ws, 4096, 2048);
  norm_rope_tv<<<dim3(13312), dim3(256), 0, stream>>>(qkv_ws, vt_ws, qw, kw, pos);
  attn_fwd<<<dim3(512), dim3(256), 0, stream>>>(qkv_ws, vt_ws, y_ws);
  gemm256<128, float><<<dim3(256), dim3(512), 0, stream>>>(y_ws, wob, out, 2048, 2048);
}

// Round 4
// 312.461 us; speedup vs baseline: 1.0397x; 1.0397x over previous
//
#include <hip/hip_runtime.h>
#include <cstdint>
#include <cmath>

typedef __bf16 bf16x8 __attribute__((ext_vector_type(8)));
typedef float  f32x4  __attribute__((ext_vector_type(4)));

#define DEVI __device__ __forceinline__

#define SEQ 4096
#define NH 8
#define NKV 4
#define HD 256
#define WIN 1024

DEVI void gload16(const void* g, void* l) {
  __builtin_amdgcn_global_load_lds((const __attribute__((address_space(1))) void*)g,
                                   (__attribute__((address_space(3))) void*)l,
                                   16, 0, 0);
}

DEVI bf16x8 ld8f(const float* p) {
  const f32x4 a = *(const f32x4*)p;
  const f32x4 b = *(const f32x4*)(p + 4);
  bf16x8 r;
#pragma unroll
  for (int j = 0; j < 4; ++j) { r[j] = (__bf16)a[j]; r[4 + j] = (__bf16)b[j]; }
  return r;
}

DEVI void st1(float* p, float v)  { *p = v; }
DEVI void st1(__bf16* p, float v) { *p = (__bf16)v; }

// raw barrier (no vmcnt(0) drain, unlike __syncthreads) + compiler memory fence
DEVI void barx() {
  asm volatile("" ::: "memory");
  __builtin_amdgcn_s_barrier();
  asm volatile("" ::: "memory");
}

// ---------------------------------------------------------------------------
// fp32 -> bf16 conversion. Wq/Wk/Wv concatenated into one 4096x2048 buffer.
// ---------------------------------------------------------------------------
__global__ __launch_bounds__(256)
void cvt_all(const float* __restrict__ x,  const float* __restrict__ wq,
             const float* __restrict__ wk, const float* __restrict__ wv,
             const float* __restrict__ wo,
             __bf16* __restrict__ xb, __bf16* __restrict__ wqkvb,
             __bf16* __restrict__ wob) {
  const size_t g = (size_t)blockIdx.x * 256 + threadIdx.x;
  const float* src; __bf16* dst; size_t off;
  if      (g < 1048576) { src = x;  dst = xb;               off = g; }
  else if (g < 1572864) { src = wq; dst = wqkvb;            off = g - 1048576; }
  else if (g < 1835008) { src = wk; dst = wqkvb + 4194304;  off = g - 1572864; }
  else if (g < 2097152) { src = wv; dst = wqkvb + 6291456;  off = g - 1835008; }
  else                  { src = wo; dst = wob;              off = g - 2097152; }
  *(bf16x8*)(dst + off * 8) = ld8f(src + off * 8);
}

// ---------------------------------------------------------------------------
// GEMM (BM=256 only): m201-style 4-phase fine interleave per K-tile.
// 16 MFMA per barrier amortizes phase overhead — verified round 3 (dropped
// below attn in top-5). Do NOT use for BM=128 (8 MFMA/barrier regressed).
// ---------------------------------------------------------------------------
template <int BM, typename TC>
__global__ __launch_bounds__(512, 2)
void gemm256(const __bf16* __restrict__ A, const __bf16* __restrict__ B,
             TC* __restrict__ C, int N, int K) {
  constexpr int AI    = BM / 128;
  constexpr int MF    = BM / 32;
  constexpr int MH    = MF / 2;
  constexpr int AUNIT = BM * 64;
  constexpr int ASZ   = 4 * AUNIT;
  constexpr int VMC   = 2 * AI + 4;
  __shared__ char lds[ASZ + 65536];

  const int tid  = threadIdx.x;
  const int lane = tid & 63;
  const int wave = tid >> 6;
  const int l15  = lane & 15;
  const int l4   = lane >> 4;
  const int wm   = wave >> 2;
  const int wn   = wave & 3;

  constexpr int nTm = 4096 / BM;
  const int lin  = blockIdx.x;
  const int xcd  = lin & 7;
  const int kk   = lin >> 3;
  const int nTn  = N >> 8;
  const int rowT = kk % nTm;
  const int colT = xcd * (nTn >> 3) + kk / nTm;
  const int row0 = rowT * BM;
  const int col0 = colT << 8;

  const int srow = tid >> 2;
  const int scol = ((tid & 3) ^ ((tid >> 3) & 3)) << 3;
  const __bf16* Asrc = A + (size_t)(row0 + srow) * K + scol;
  const __bf16* Bsrc = B + (size_t)(col0 + srow) * K + scol;

  const int swz  = (l4 ^ ((l15 >> 1) & 3)) << 4;
  const int aoff = (wm * (BM / 2) + l15) * 64 + swz;
  const int boff = ((wn << 6) + l15) * 64 + swz;

  auto stA = [&](int kx, int h) {
    int k0 = kx << 6; if (k0 >= K) k0 = 0;
    const __bf16* s = Asrc + k0 + (h << 5);
    char* d = lds + ((kx & 1) * 2 + h) * AUNIT + wave * 1024;
#pragma unroll
    for (int i = 0; i < AI; ++i)
      gload16(s + (size_t)(i << 7) * K, d + i * 8192);
  };
  auto stB = [&](int kx, int h) {
    int k0 = kx << 6; if (k0 >= K) k0 = 0;
    const __bf16* s = Bsrc + k0 + (h << 5);
    char* d = lds + ASZ + ((kx & 1) * 2 + h) * 16384 + wave * 1024;
#pragma unroll
    for (int i = 0; i < 2; ++i)
      gload16(s + (size_t)(i << 7) * K, d + i * 8192);
  };

  f32x4 acc[MF][4] = {};

  stA(0, 0); stB(0, 0); stA(0, 1); stB(0, 1); stA(1, 0); stB(1, 0);
  asm volatile("s_waitcnt vmcnt(%0)" :: "i"(VMC) : "memory");
  barx();

  const int NT = K >> 6;
  for (int kt = 0; kt < NT; ++kt) {
    const int bb = (kt & 1) * 2;
    bf16x8 bfr[4];
    bf16x8 af[MH];

    auto rd = [&](int h, int mg, bool readB) {
      const char* pa = lds + (bb + h) * AUNIT + aoff;
#pragma unroll
      for (int m = 0; m < MH; ++m)
        af[m] = *(const bf16x8*)(pa + ((mg * MH + m) << 10));
      if (readB) {
        const char* pb = lds + ASZ + (bb + h) * 16384 + boff;
#pragma unroll
        for (int n = 0; n < 4; ++n)
          bfr[n] = *(const bf16x8*)(pb + (n << 10));
      }
    };
    auto mm = [&](int mg) {
      barx();
      __builtin_amdgcn_s_setprio(1);
#pragma unroll
      for (int m = 0; m < MH; ++m)
#pragma unroll
        for (int n = 0; n < 4; ++n)
          acc[mg * MH + m][n] =
              __builtin_amdgcn_mfma_f32_16x16x32_bf16(af[m], bfr[n], acc[mg * MH + m][n], 0, 0, 0);
      __builtin_amdgcn_s_setprio(0);
    };

    // p0
    rd(0, 0, true);
    stA(kt + 1, 1);
    mm(0);
    // p1
    rd(0, 1, false);
    stB(kt + 1, 1);
    asm volatile("s_waitcnt vmcnt(%0)" :: "i"(VMC) : "memory");
    mm(1);
    // p2
    rd(1, 0, true);
    stA(kt + 2, 0);
    mm(0);
    // p3
    rd(1, 1, false);
    stB(kt + 2, 0);
    asm volatile("s_waitcnt vmcnt(%0)" :: "i"(VMC) : "memory");
    mm(1);
  }
  asm volatile("s_waitcnt vmcnt(0)" ::: "memory");

#pragma unroll
  for (int mf = 0; mf < MF; ++mf) {
    const int rb = row0 + wm * (BM / 2) + (mf >> 2) * 64 + (mf & 3) * 16 + (l4 << 2);
#pragma unroll
    for (int reg = 0; reg < 4; ++reg) {
      TC* crow = C + (size_t)(rb + reg) * N + col0 + (wn << 6) + l15;
#pragma unroll
      for (int n = 0; n < 4; ++n) st1(crow + (n << 4), acc[mf][n][reg]);
    }
  }
}

// ---------------------------------------------------------------------------
// GEMM 2-phase (round-1 structure) — used for the out-proj (BM=128).
// At BM=128 the 4-phase split leaves only 8 MFMA/barrier and regressed
// (round-3 post-mortem); the coarse 2-phase schedule measured better.
// ---------------------------------------------------------------------------
template <int BM, typename TC>
__global__ __launch_bounds__(512, 2)
void gemm2ph(const __bf16* __restrict__ A, const __bf16* __restrict__ B,
             TC* __restrict__ C, int N, int K) {
  constexpr int AI    = BM / 128;
  constexpr int MF    = BM / 32;
  constexpr int AUNIT = BM * 64;
  constexpr int ASZ   = 4 * AUNIT;
  constexpr int VMC   = 2 * (AI + 2);
  __shared__ char lds[ASZ + 65536];

  const int tid  = threadIdx.x;
  const int lane = tid & 63;
  const int wave = tid >> 6;
  const int l15  = lane & 15;
  const int l4   = lane >> 4;
  const int wm   = wave >> 2;
  const int wn   = wave & 3;

  constexpr int nTm = 4096 / BM;
  const int lin  = blockIdx.x;
  const int xcd  = lin & 7;
  const int kk   = lin >> 3;
  const int nTn  = N >> 8;
  const int rowT = kk % nTm;
  const int colT = xcd * (nTn >> 3) + kk / nTm;
  const int row0 = rowT * BM;
  const int col0 = colT << 8;

  const int srow = tid >> 2;
  const int scol = ((tid & 3) ^ ((tid >> 3) & 3)) << 3;
  const __bf16* Asrc = A + (size_t)(row0 + srow) * K + scol;
  const __bf16* Bsrc = B + (size_t)(col0 + srow) * K + scol;

  const int swz  = (l4 ^ ((l15 >> 1) & 3)) << 4;
  const int aoff = (wm * (BM / 2) + l15) * 64 + swz;
  const int boff = ((wn << 6) + l15) * 64 + swz;

  auto stA = [&](int kx, int h, int b) {
    int k0 = kx << 6; if (k0 >= K) k0 = 0;
    const __bf16* s = Asrc + k0 + (h << 5);
    char* d = lds + (b * 2 + h) * AUNIT + wave * 1024;
#pragma unroll
    for (int i = 0; i < AI; ++i)
      gload16(s + (size_t)(i << 7) * K, d + i * 8192);
  };
  auto stB = [&](int kx, int h, int b) {
    int k0 = kx << 6; if (k0 >= K) k0 = 0;
    const __bf16* s = Bsrc + k0 + (h << 5);
    char* d = lds + ASZ + (b * 2 + h) * 16384 + wave * 1024;
#pragma unroll
    for (int i = 0; i < 2; ++i)
      gload16(s + (size_t)(i << 7) * K, d + i * 8192);
  };

  f32x4 acc[MF][4] = {};

  stA(0, 0, 0); stB(0, 0, 0);
  stA(0, 1, 0); stB(0, 1, 0);
  stA(1, 0, 1); stB(1, 0, 1);

  const int NT = K >> 6;
  for (int kt = 0; kt < NT; ++kt) {
    const int b = kt & 1, nb = b ^ 1;
#pragma unroll
    for (int half = 0; half < 2; ++half) {
      asm volatile("s_waitcnt vmcnt(%0)" :: "i"(VMC) : "memory");
      barx();
      bf16x8 af[4], ag[4], bfr[4];
      const char* pa = lds + (b * 2 + half) * AUNIT + aoff;
      const char* pb = lds + ASZ + (b * 2 + half) * 16384 + boff;
#pragma unroll
      for (int m = 0; m < 4; ++m) af[m] = *(const bf16x8*)(pa + (m << 10));
#pragma unroll
      for (int n = 0; n < 4; ++n) bfr[n] = *(const bf16x8*)(pb + (n << 10));
      if constexpr (BM == 256) {
#pragma unroll
        for (int m = 0; m < 4; ++m) ag[m] = *(const bf16x8*)(pa + 4096 + (m << 10));
      }
      if (half == 0) { stA(kt + 1, 1, nb); stB(kt + 1, 1, nb); }
      else           { stA(kt + 2, 0, b);  stB(kt + 2, 0, b);  }
      __builtin_amdgcn_s_setprio(1);
#pragma unroll
      for (int m = 0; m < 4; ++m)
#pragma unroll
        for (int n = 0; n < 4; ++n)
          acc[m][n] = __builtin_amdgcn_mfma_f32_16x16x32_bf16(af[m], bfr[n], acc[m][n], 0, 0, 0);
      if constexpr (BM == 256) {
#pragma unroll
        for (int m = 0; m < 4; ++m)
#pragma unroll
          for (int n = 0; n < 4; ++n)
            acc[4 + m][n] = __builtin_amdgcn_mfma_f32_16x16x32_bf16(ag[m], bfr[n], acc[4 + m][n], 0, 0, 0);
      }
      __builtin_amdgcn_s_setprio(0);
    }
  }

#pragma unroll
  for (int mf = 0; mf < MF; ++mf) {
    const int rb = row0 + wm * (BM / 2) + (mf >> 2) * 64 + (mf & 3) * 16 + (l4 << 2);
#pragma unroll
    for (int reg = 0; reg < 4; ++reg) {
      TC* crow = C + (size_t)(rb + reg) * N + col0 + (wn << 6) + l15;
#pragma unroll
      for (int n = 0; n < 4; ++n) st1(crow + (n << 4), acc[mf][n][reg]);
    }
  }
}

// ---------------------------------------------------------------------------
// Merged: per-head RMSNorm+RoPE (blocks 0..12287) and V-transpose (12288+).
// ---------------------------------------------------------------------------
__global__ __launch_bounds__(256)
void norm_rope_tv(__bf16* __restrict__ qkv, __bf16* __restrict__ Vt,
                  const float* __restrict__ qw, const float* __restrict__ kw,
                  const int* __restrict__ pos) {
  if (blockIdx.x < 12288) {
    const int gw   = blockIdx.x * 4 + (threadIdx.x >> 6);
    const int lane = threadIdx.x & 63;
    __bf16* base; const float* w; int t;
    if (gw < SEQ * NH) {
      t = gw >> 3;
      base = qkv + (size_t)t * 4096 + (gw & 7) * HD;
      w = qw;
    } else {
      const int g = gw - SEQ * NH;
      t = g >> 2;
      base = qkv + (size_t)t * 4096 + 2048 + (g & 3) * HD;
      w = kw;
    }

    const int d0 = lane * 4;
    float v[4]; float ss = 0.f;
#pragma unroll
    for (int j = 0; j < 4; ++j) { v[j] = (float)base[d0 + j]; ss += v[j] * v[j]; }
#pragma unroll
    for (int off = 1; off < 64; off <<= 1) ss += __shfl_xor(ss, off);
    const float rms = rsqrtf(ss * (1.0f / 256.0f) + 1e-6f);
    const float p = (float)pos[t];

    float n[4];
#pragma unroll
    for (int j = 0; j < 4; ++j) n[j] = v[j] * rms * w[d0 + j];

    float outv[4];
#pragma unroll
    for (int e = 0; e < 4; e += 2) {
      const int i0 = d0 + e, i1 = i0 + 1;
      const float f0 = exp2f(-(float)(i0 & 127) * 0.103810253f);
      const float f1 = exp2f(-(float)(i1 & 127) * 0.103810253f);
      float s0, cc0, s1, cc1;
      sincosf(p * f0, &s0, &cc0);
      sincosf(p * f1, &s1, &cc1);
      outv[e]     = n[e] * cc0 - n[e + 1] * s0;
      outv[e + 1] = n[e + 1] * cc1 + n[e] * s1;
    }
#pragma unroll
    for (int j = 0; j < 4; ++j) base[d0 + j] = (__bf16)outv[j];
  } else {
    __shared__ __bf16 tile[64][72];
    const int b   = blockIdx.x - 12288;       // 0..1023
    const int tid = threadIdx.x;
    const int tb  = (b & 63) * 64;
    const int yy  = b >> 6;                   // 0..15
    const int kvh = yy >> 2;
    const int db  = (yy & 3) * 64;
#pragma unroll
    for (int i = 0; i < 2; ++i) {
      const int s = i * 256 + tid;
      const int r = s >> 3, c = (s & 7) * 8;
      bf16x8 val = *(const bf16x8*)(qkv + (size_t)(tb + r) * 4096 + 3072 + kvh * HD + db + c);
#pragma unroll
      for (int j = 0; j < 8; ++j) tile[r][c + j] = val[j];
    }
    __syncthreads();
#pragma unroll
    for (int i = 0; i < 2; ++i) {
      const int s = i * 256 + tid;
      const int r = s >> 3, c = (s & 7) * 8;
      bf16x8 outv;
#pragma unroll
      for (int j = 0; j < 8; ++j) outv[j] = tile[c + j][r];
      *(bf16x8*)(Vt + (size_t)(kvh * HD + db + r) * SEQ + tb + c) = outv;
    }
  }
}

// ---------------------------------------------------------------------------
// Sliding-window flash attention v3: tile-level software pipeline.
//   S(kt+1) is computed from the resident dbuf slot BEFORE softmax(kt)/PV(kt),
//   so its 16 MFMAs complete in the shadow of softmax VALU + PV — the QK
//   dependency chain leaves the critical path. QK uses 4 accumulation chains
//   (2 kn x 2 k-halves) to halve dependent-MFMA latency.
// Sync (issue order: per tile, K then V; 4+4 loads, all per-wave uniform):
//   prologue: K(t0)->s0, V(t0)->s0, K(t0+1)->s1, V(t0+1)->s1;
//             vmcnt(12)+barx  -> K(t0) landed; compute S(t0).
//   iter kt (slot p=(kt-kt0)&1, np=p^1):
//     vmcnt(4)+barx  -> all but the newest 4 (V of the youngest staged tile)
//                       done => K(kt+1) landed (for S-next), V(kt) landed.
//     stage K(kt+2)->K[p]   (K[p]=K(kt) was read at iter kt-1; barrier passed)
//     S_next = QK(kt+1) from K[np]
//     softmax(kt) on S_cur -> Ps, l_run;  PV(kt) from V[p]
//     barx(); stage V(kt+2)->V[p]  (all waves finished PV reads of V(kt))
//   tails are clamped re-issues (real, finite data; masked or discarded).
//   exit: vmcnt(0).
// ---------------------------------------------------------------------------
__global__ __launch_bounds__(256, 2)
void attn_fwd(const __bf16* __restrict__ qkv, const __bf16* __restrict__ Vt,
              __bf16* __restrict__ Y) {
  __shared__ char klds[2][16384];      // [slot][32 key][32 dim] rows of 64B, swz
  __shared__ char vlds[2][16384];      // [slot][256 dim][32 key] rows of 64B, swz
  __shared__ __bf16 Ps[4][16][40];     // per-wave P (padded rows)
  const int tid  = threadIdx.x;
  const int lane = tid & 63;
  const int wave = tid >> 6;
  const int l15  = lane & 15;
  const int l4   = lane >> 4;
  const int lin  = blockIdx.x;
  const int head = lin & 7;            // head-per-XCD pinning
  const int q0   = (lin >> 3) * 64;
  const int kvh  = head >> 1;
  const int qw   = q0 + wave * 16;

  // Q fragments: A[m=lane&15][k=(lane>>4)*8+j]; pre-scale 1/16 (exact pow2)
  bf16x8 qf[8];
  const __bf16* qrow = qkv + (size_t)(qw + l15) * 4096 + head * HD;
#pragma unroll
  for (int ks = 0; ks < 8; ++ks) {
    bf16x8 t = *(const bf16x8*)(qrow + ks * 32 + l4 * 8);
#pragma unroll
    for (int j = 0; j < 8; ++j) t[j] = (__bf16)((float)t[j] * 0.0625f);
    qf[ks] = t;
  }

  f32x4 o[16] = {};
  float l_run[4] = {0.f, 0.f, 0.f, 0.f};

  int lo = q0 - (WIN - 1); if (lo < 0) lo = 0;
  const int kt0 = lo >> 5;
  const int kt1 = (q0 + 63) >> 5;      // >= kt0+1 always (>=2 tiles)
  const int kbmax = kt1 << 5;

  const int skey = (tid >> 2) & 31;                 // K: key row
  const int sdim = tid >> 2;                        // V: dim row (+ i*64)
  const int sg   = (tid & 3) ^ ((tid >> 3) & 3);    // swizzled source col16
  const int sth  = tid >> 7;

  auto stK = [&](int kt, int b) {
    int kb = kt << 5; if (kb > kbmax) kb = kbmax;   // clamped dummy re-issue
    const __bf16* s = qkv + (size_t)(kb + skey) * 4096 + 2048 + kvh * HD
                          + sth * 32 + sg * 8;
    char* d = klds[b] + wave * 1024;
#pragma unroll
    for (int i = 0; i < 4; ++i)
      gload16(s + i * 64, d + i * 4096);
  };
  auto stV = [&](int kt, int b) {
    int kb = kt << 5; if (kb > kbmax) kb = kbmax;
    const __bf16* s = Vt + ((size_t)kvh * HD + sdim) * SEQ + kb + sg * 8;
    char* d = vlds[b] + wave * 1024;
#pragma unroll
    for (int i = 0; i < 4; ++i)
      gload16(s + (size_t)i * 64 * SEQ, d + i * 4096);
  };

  const int rswz = (l4 ^ ((l15 >> 1) & 3)) << 4;

  // QK with 4 accumulation chains (2 kn x 2 k-halves)
  auto computeS = [&](const char* kbase, f32x4* s) {
    f32x4 a0 = {}, a1 = {}, b0 = {}, b1 = {};
    __builtin_amdgcn_s_setprio(1);
#pragma unroll
    for (int ks = 0; ks < 4; ++ks) {
      bf16x8 k0 = *(const bf16x8*)(kbase + (ks * 32 + l15) * 64 + rswz);
      bf16x8 k1 = *(const bf16x8*)(kbase + (ks * 32 + 16 + l15) * 64 + rswz);
      a0 = __builtin_amdgcn_mfma_f32_16x16x32_bf16(qf[ks], k0, a0, 0, 0, 0);
      b0 = __builtin_amdgcn_mfma_f32_16x16x32_bf16(qf[ks], k1, b0, 0, 0, 0);
    }
#pragma unroll
    for (int ks = 4; ks < 8; ++ks) {
      bf16x8 k0 = *(const bf16x8*)(kbase + (ks * 32 + l15) * 64 + rswz);
      bf16x8 k1 = *(const bf16x8*)(kbase + (ks * 32 + 16 + l15) * 64 + rswz);
      a1 = __builtin_amdgcn_mfma_f32_16x16x32_bf16(qf[ks], k0, a1, 0, 0, 0);
      b1 = __builtin_amdgcn_mfma_f32_16x16x32_bf16(qf[ks], k1, b1, 0, 0, 0);
    }
    __builtin_amdgcn_s_setprio(0);
    s[0] = a0 + a1;
    s[1] = b0 + b1;
  };

  // prologue
  stK(kt0, 0);     stV(kt0, 0);
  stK(kt0 + 1, 1); stV(kt0 + 1, 1);
  asm volatile("s_waitcnt vmcnt(12)" ::: "memory");
  barx();
  f32x4 sc[2];
  computeS(klds[0], sc);

  for (int kt = kt0; kt <= kt1; ++kt) {
    const int p  = (kt - kt0) & 1, np = p ^ 1;
    const int kb = kt << 5;

    asm volatile("s_waitcnt vmcnt(4)" ::: "memory");
    barx();

    // refill K[p] (its tile was consumed last iteration; barrier passed)
    stK(kt + 2, p);

    // S(kt+1) — completes in the shadow of softmax+PV below
    f32x4 sn[2];
    computeS(klds[np], sn);

    // fixed-max softmax on S_cur: p = exp(min(s,34)-34); masked -> 0
#pragma unroll
    for (int reg = 0; reg < 4; ++reg) {
      const int r  = l4 * 4 + reg;
      const int qg = qw + r;
      float ps = 0.f;
#pragma unroll
      for (int kn = 0; kn < 2; ++kn) {
        const int kg = kb + kn * 16 + l15;
        const bool ok = (kg <= qg) && (kg > qg - WIN);
        const float pv = ok ? __expf(fminf(sc[kn][reg], 34.f) - 34.f) : 0.f;
        ps += pv;
        Ps[wave][r][kn * 16 + l15] = (__bf16)pv;
      }
      l_run[reg] += ps;
    }

    // O += P V   (Ps per-wave; intra-wave LDS ordering needs no barrier)
    const char* vbase = vlds[p];
    bf16x8 pf = *(const bf16x8*)&Ps[wave][l15][l4 * 8];
    __builtin_amdgcn_s_setprio(1);
#pragma unroll
    for (int dn = 0; dn < 16; ++dn) {
      bf16x8 vf = *(const bf16x8*)(vbase + (dn * 16 + l15) * 64 + rswz);
      o[dn] = __builtin_amdgcn_mfma_f32_16x16x32_bf16(pf, vf, o[dn], 0, 0, 0);
    }
    __builtin_amdgcn_s_setprio(0);

    barx();
    stV(kt + 2, p);
    sc[0] = sn[0]; sc[1] = sn[1];
  }
  // no DMA in flight at exit (LDS may be reassigned to the next block)
  asm volatile("s_waitcnt vmcnt(0)" ::: "memory");

  // epilogue: reduce l across the 16 lanes sharing each row, then scale
#pragma unroll
  for (int reg = 0; reg < 4; ++reg) {
#pragma unroll
    for (int off = 1; off < 16; off <<= 1)
      l_run[reg] += __shfl_xor(l_run[reg], off);
    const float inv = 1.0f / l_run[reg];
    const int q = qw + l4 * 4 + reg;
    __bf16* yrow = Y + ((size_t)q * NH + head) * HD + l15;
#pragma unroll
    for (int dn = 0; dn < 16; ++dn)
      yrow[dn * 16] = (__bf16)(o[dn][reg] * inv);
  }
}

// ---------------------------------------------------------------------------
extern "C" void kernel_launch(void* const* d_in, const int* in_sizes, int n_in,
                              void* d_out, int out_size, void* d_ws, size_t ws_size,
                              hipStream_t stream) {
  (void)in_sizes; (void)n_in; (void)out_size; (void)ws_size;
  const float* x   = (const float*)d_in[0];
  const int*   pos = (const int*)d_in[1];
  const float* Wq  = (const float*)d_in[2];
  const float* Wk  = (const float*)d_in[3];
  const float* Wv  = (const float*)d_in[4];
  const float* Wo  = (const float*)d_in[5];
  const float* qw  = (const float*)d_in[6];
  const float* kw  = (const float*)d_in[7];
  float* out = (float*)d_out;

  char* ws = (char*)d_ws;
  const size_t MB = 1024 * 1024;
  __bf16* qkv_ws = (__bf16*)(ws);             // 32 MiB  [4096][4096]
  __bf16* vt_ws  = (__bf16*)(ws + 32 * MB);   //  8 MiB  [4][256][4096]
  __bf16* y_ws   = (__bf16*)(ws + 40 * MB);   // 16 MiB  [4096][2048]
  __bf16* xb     = (__bf16*)(ws + 56 * MB);   // 16 MiB
  __bf16* wqkvb  = (__bf16*)(ws + 72 * MB);   // 16 MiB  [4096][2048]
  __bf16* wob    = (__bf16*)(ws + 88 * MB);   //  8 MiB  (total 96 MiB)

  cvt_all<<<dim3(10240), dim3(256), 0, stream>>>(x, Wq, Wk, Wv, Wo, xb, wqkvb, wob);
  gemm256<256, __bf16><<<dim3(256), dim3(512), 0, stream>>>(xb, wqkvb, qkv_ws, 4096, 2048);
  norm_rope_tv<<<dim3(13312), dim3(256), 0, stream>>>(qkv_ws, vt_ws, qw, kw, pos);
  attn_fwd<<<dim3(512), dim3(256), 0, stream>>>(qkv_ws, vt_ws, y_ws);
  gemm2ph<128, float><<<dim3(256), dim3(512), 0, stream>>>(y_ws, wob, out, 2048, 2048);
}

// Round 5
// 305.822 us; speedup vs baseline: 1.0623x; 1.0217x over previous
//
#include <hip/hip_runtime.h>
#include <cstdint>
#include <cmath>

typedef __bf16 bf16x8 __attribute__((ext_vector_type(8)));
typedef float  f32x4  __attribute__((ext_vector_type(4)));

#define DEVI __device__ __forceinline__

#define SEQ 4096
#define NH 8
#define NKV 4
#define HD 256
#define WIN 1024

DEVI void gload16(const void* g, void* l) {
  __builtin_amdgcn_global_load_lds((const __attribute__((address_space(1))) void*)g,
                                   (__attribute__((address_space(3))) void*)l,
                                   16, 0, 0);
}

DEVI bf16x8 ld8f(const float* p) {
  const f32x4 a = *(const f32x4*)p;
  const f32x4 b = *(const f32x4*)(p + 4);
  bf16x8 r;
#pragma unroll
  for (int j = 0; j < 4; ++j) { r[j] = (__bf16)a[j]; r[4 + j] = (__bf16)b[j]; }
  return r;
}

DEVI void st1(float* p, float v)  { *p = v; }
DEVI void st1(__bf16* p, float v) { *p = (__bf16)v; }

// raw barrier (no vmcnt(0) drain, unlike __syncthreads) + compiler memory fence
DEVI void barx() {
  asm volatile("" ::: "memory");
  __builtin_amdgcn_s_barrier();
  asm volatile("" ::: "memory");
}

// ---------------------------------------------------------------------------
// fp32 -> bf16 conversion. Wq/Wk/Wv concatenated into one 4096x2048 buffer.
// ---------------------------------------------------------------------------
__global__ __launch_bounds__(256)
void cvt_all(const float* __restrict__ x,  const float* __restrict__ wq,
             const float* __restrict__ wk, const float* __restrict__ wv,
             const float* __restrict__ wo,
             __bf16* __restrict__ xb, __bf16* __restrict__ wqkvb,
             __bf16* __restrict__ wob) {
  const size_t g = (size_t)blockIdx.x * 256 + threadIdx.x;
  const float* src; __bf16* dst; size_t off;
  if      (g < 1048576) { src = x;  dst = xb;               off = g; }
  else if (g < 1572864) { src = wq; dst = wqkvb;            off = g - 1048576; }
  else if (g < 1835008) { src = wk; dst = wqkvb + 4194304;  off = g - 1572864; }
  else if (g < 2097152) { src = wv; dst = wqkvb + 6291456;  off = g - 1835008; }
  else                  { src = wo; dst = wob;              off = g - 2097152; }
  *(bf16x8*)(dst + off * 8) = ld8f(src + off * 8);
}

// ---------------------------------------------------------------------------
// GEMM (BM=256 only): m201-style 4-phase fine interleave per K-tile.
// 16 MFMA per barrier amortizes phase overhead — validated rounds 3/4.
// Do NOT use for BM=128 (8 MFMA/barrier regressed, round-3 post-mortem).
// ---------------------------------------------------------------------------
template <int BM, typename TC>
__global__ __launch_bounds__(512, 2)
void gemm256(const __bf16* __restrict__ A, const __bf16* __restrict__ B,
             TC* __restrict__ C, int N, int K) {
  constexpr int AI    = BM / 128;
  constexpr int MF    = BM / 32;
  constexpr int MH    = MF / 2;
  constexpr int AUNIT = BM * 64;
  constexpr int ASZ   = 4 * AUNIT;
  constexpr int VMC   = 2 * AI + 4;
  __shared__ char lds[ASZ + 65536];

  const int tid  = threadIdx.x;
  const int lane = tid & 63;
  const int wave = tid >> 6;
  const int l15  = lane & 15;
  const int l4   = lane >> 4;
  const int wm   = wave >> 2;
  const int wn   = wave & 3;

  constexpr int nTm = 4096 / BM;
  const int lin  = blockIdx.x;
  const int xcd  = lin & 7;
  const int kk   = lin >> 3;
  const int nTn  = N >> 8;
  const int rowT = kk % nTm;
  const int colT = xcd * (nTn >> 3) + kk / nTm;
  const int row0 = rowT * BM;
  const int col0 = colT << 8;

  const int srow = tid >> 2;
  const int scol = ((tid & 3) ^ ((tid >> 3) & 3)) << 3;
  const __bf16* Asrc = A + (size_t)(row0 + srow) * K + scol;
  const __bf16* Bsrc = B + (size_t)(col0 + srow) * K + scol;

  const int swz  = (l4 ^ ((l15 >> 1) & 3)) << 4;
  const int aoff = (wm * (BM / 2) + l15) * 64 + swz;
  const int boff = ((wn << 6) + l15) * 64 + swz;

  auto stA = [&](int kx, int h) {
    int k0 = kx << 6; if (k0 >= K) k0 = 0;
    const __bf16* s = Asrc + k0 + (h << 5);
    char* d = lds + ((kx & 1) * 2 + h) * AUNIT + wave * 1024;
#pragma unroll
    for (int i = 0; i < AI; ++i)
      gload16(s + (size_t)(i << 7) * K, d + i * 8192);
  };
  auto stB = [&](int kx, int h) {
    int k0 = kx << 6; if (k0 >= K) k0 = 0;
    const __bf16* s = Bsrc + k0 + (h << 5);
    char* d = lds + ASZ + ((kx & 1) * 2 + h) * 16384 + wave * 1024;
#pragma unroll
    for (int i = 0; i < 2; ++i)
      gload16(s + (size_t)(i << 7) * K, d + i * 8192);
  };

  f32x4 acc[MF][4] = {};

  stA(0, 0); stB(0, 0); stA(0, 1); stB(0, 1); stA(1, 0); stB(1, 0);
  asm volatile("s_waitcnt vmcnt(%0)" :: "i"(VMC) : "memory");
  barx();

  const int NT = K >> 6;
  for (int kt = 0; kt < NT; ++kt) {
    const int bb = (kt & 1) * 2;
    bf16x8 bfr[4];
    bf16x8 af[MH];

    auto rd = [&](int h, int mg, bool readB) {
      const char* pa = lds + (bb + h) * AUNIT + aoff;
#pragma unroll
      for (int m = 0; m < MH; ++m)
        af[m] = *(const bf16x8*)(pa + ((mg * MH + m) << 10));
      if (readB) {
        const char* pb = lds + ASZ + (bb + h) * 16384 + boff;
#pragma unroll
        for (int n = 0; n < 4; ++n)
          bfr[n] = *(const bf16x8*)(pb + (n << 10));
      }
    };
    auto mm = [&](int mg) {
      barx();
      __builtin_amdgcn_s_setprio(1);
#pragma unroll
      for (int m = 0; m < MH; ++m)
#pragma unroll
        for (int n = 0; n < 4; ++n)
          acc[mg * MH + m][n] =
              __builtin_amdgcn_mfma_f32_16x16x32_bf16(af[m], bfr[n], acc[mg * MH + m][n], 0, 0, 0);
      __builtin_amdgcn_s_setprio(0);
    };

    // p0
    rd(0, 0, true);
    stA(kt + 1, 1);
    mm(0);
    // p1
    rd(0, 1, false);
    stB(kt + 1, 1);
    asm volatile("s_waitcnt vmcnt(%0)" :: "i"(VMC) : "memory");
    mm(1);
    // p2
    rd(1, 0, true);
    stA(kt + 2, 0);
    mm(0);
    // p3
    rd(1, 1, false);
    stB(kt + 2, 0);
    asm volatile("s_waitcnt vmcnt(%0)" :: "i"(VMC) : "memory");
    mm(1);
  }
  asm volatile("s_waitcnt vmcnt(0)" ::: "memory");

#pragma unroll
  for (int mf = 0; mf < MF; ++mf) {
    const int rb = row0 + wm * (BM / 2) + (mf >> 2) * 64 + (mf & 3) * 16 + (l4 << 2);
#pragma unroll
    for (int reg = 0; reg < 4; ++reg) {
      TC* crow = C + (size_t)(rb + reg) * N + col0 + (wn << 6) + l15;
#pragma unroll
      for (int n = 0; n < 4; ++n) st1(crow + (n << 4), acc[mf][n][reg]);
    }
  }
}

// ---------------------------------------------------------------------------
// GEMM 2-phase (round-1 structure) — used for the out-proj (BM=128).
// At BM=128 the 4-phase split leaves only 8 MFMA/barrier and regressed
// (round-3 post-mortem); this coarse 2-phase schedule measured better (r4).
// ---------------------------------------------------------------------------
template <int BM, typename TC>
__global__ __launch_bounds__(512, 2)
void gemm2ph(const __bf16* __restrict__ A, const __bf16* __restrict__ B,
             TC* __restrict__ C, int N, int K) {
  constexpr int AI    = BM / 128;
  constexpr int MF    = BM / 32;
  constexpr int AUNIT = BM * 64;
  constexpr int ASZ   = 4 * AUNIT;
  constexpr int VMC   = 2 * (AI + 2);
  __shared__ char lds[ASZ + 65536];

  const int tid  = threadIdx.x;
  const int lane = tid & 63;
  const int wave = tid >> 6;
  const int l15  = lane & 15;
  const int l4   = lane >> 4;
  const int wm   = wave >> 2;
  const int wn   = wave & 3;

  constexpr int nTm = 4096 / BM;
  const int lin  = blockIdx.x;
  const int xcd  = lin & 7;
  const int kk   = lin >> 3;
  const int nTn  = N >> 8;
  const int rowT = kk % nTm;
  const int colT = xcd * (nTn >> 3) + kk / nTm;
  const int row0 = rowT * BM;
  const int col0 = colT << 8;

  const int srow = tid >> 2;
  const int scol = ((tid & 3) ^ ((tid >> 3) & 3)) << 3;
  const __bf16* Asrc = A + (size_t)(row0 + srow) * K + scol;
  const __bf16* Bsrc = B + (size_t)(col0 + srow) * K + scol;

  const int swz  = (l4 ^ ((l15 >> 1) & 3)) << 4;
  const int aoff = (wm * (BM / 2) + l15) * 64 + swz;
  const int boff = ((wn << 6) + l15) * 64 + swz;

  auto stA = [&](int kx, int h, int b) {
    int k0 = kx << 6; if (k0 >= K) k0 = 0;
    const __bf16* s = Asrc + k0 + (h << 5);
    char* d = lds + (b * 2 + h) * AUNIT + wave * 1024;
#pragma unroll
    for (int i = 0; i < AI; ++i)
      gload16(s + (size_t)(i << 7) * K, d + i * 8192);
  };
  auto stB = [&](int kx, int h, int b) {
    int k0 = kx << 6; if (k0 >= K) k0 = 0;
    const __bf16* s = Bsrc + k0 + (h << 5);
    char* d = lds + ASZ + (b * 2 + h) * 16384 + wave * 1024;
#pragma unroll
    for (int i = 0; i < 2; ++i)
      gload16(s + (size_t)(i << 7) * K, d + i * 8192);
  };

  f32x4 acc[MF][4] = {};

  stA(0, 0, 0); stB(0, 0, 0);
  stA(0, 1, 0); stB(0, 1, 0);
  stA(1, 0, 1); stB(1, 0, 1);

  const int NT = K >> 6;
  for (int kt = 0; kt < NT; ++kt) {
    const int b = kt & 1, nb = b ^ 1;
#pragma unroll
    for (int half = 0; half < 2; ++half) {
      asm volatile("s_waitcnt vmcnt(%0)" :: "i"(VMC) : "memory");
      barx();
      bf16x8 af[4], ag[4], bfr[4];
      const char* pa = lds + (b * 2 + half) * AUNIT + aoff;
      const char* pb = lds + ASZ + (b * 2 + half) * 16384 + boff;
#pragma unroll
      for (int m = 0; m < 4; ++m) af[m] = *(const bf16x8*)(pa + (m << 10));
#pragma unroll
      for (int n = 0; n < 4; ++n) bfr[n] = *(const bf16x8*)(pb + (n << 10));
      if constexpr (BM == 256) {
#pragma unroll
        for (int m = 0; m < 4; ++m) ag[m] = *(const bf16x8*)(pa + 4096 + (m << 10));
      }
      if (half == 0) { stA(kt + 1, 1, nb); stB(kt + 1, 1, nb); }
      else           { stA(kt + 2, 0, b);  stB(kt + 2, 0, b);  }
      __builtin_amdgcn_s_setprio(1);
#pragma unroll
      for (int m = 0; m < 4; ++m)
#pragma unroll
        for (int n = 0; n < 4; ++n)
          acc[m][n] = __builtin_amdgcn_mfma_f32_16x16x32_bf16(af[m], bfr[n], acc[m][n], 0, 0, 0);
      if constexpr (BM == 256) {
#pragma unroll
        for (int m = 0; m < 4; ++m)
#pragma unroll
          for (int n = 0; n < 4; ++n)
            acc[4 + m][n] = __builtin_amdgcn_mfma_f32_16x16x32_bf16(ag[m], bfr[n], acc[4 + m][n], 0, 0, 0);
      }
      __builtin_amdgcn_s_setprio(0);
    }
  }

#pragma unroll
  for (int mf = 0; mf < MF; ++mf) {
    const int rb = row0 + wm * (BM / 2) + (mf >> 2) * 64 + (mf & 3) * 16 + (l4 << 2);
#pragma unroll
    for (int reg = 0; reg < 4; ++reg) {
      TC* crow = C + (size_t)(rb + reg) * N + col0 + (wn << 6) + l15;
#pragma unroll
      for (int n = 0; n < 4; ++n) st1(crow + (n << 4), acc[mf][n][reg]);
    }
  }
}

// ---------------------------------------------------------------------------
// Merged: per-head RMSNorm+RoPE (blocks 0..12287) and V-transpose (12288+).
// ---------------------------------------------------------------------------
__global__ __launch_bounds__(256)
void norm_rope_tv(__bf16* __restrict__ qkv, __bf16* __restrict__ Vt,
                  const float* __restrict__ qw, const float* __restrict__ kw,
                  const int* __restrict__ pos) {
  if (blockIdx.x < 12288) {
    const int gw   = blockIdx.x * 4 + (threadIdx.x >> 6);
    const int lane = threadIdx.x & 63;
    __bf16* base; const float* w; int t;
    if (gw < SEQ * NH) {
      t = gw >> 3;
      base = qkv + (size_t)t * 4096 + (gw & 7) * HD;
      w = qw;
    } else {
      const int g = gw - SEQ * NH;
      t = g >> 2;
      base = qkv + (size_t)t * 4096 + 2048 + (g & 3) * HD;
      w = kw;
    }

    const int d0 = lane * 4;
    float v[4]; float ss = 0.f;
#pragma unroll
    for (int j = 0; j < 4; ++j) { v[j] = (float)base[d0 + j]; ss += v[j] * v[j]; }
#pragma unroll
    for (int off = 1; off < 64; off <<= 1) ss += __shfl_xor(ss, off);
    const float rms = rsqrtf(ss * (1.0f / 256.0f) + 1e-6f);
    const float p = (float)pos[t];

    float n[4];
#pragma unroll
    for (int j = 0; j < 4; ++j) n[j] = v[j] * rms * w[d0 + j];

    float outv[4];
#pragma unroll
    for (int e = 0; e < 4; e += 2) {
      const int i0 = d0 + e, i1 = i0 + 1;
      const float f0 = exp2f(-(float)(i0 & 127) * 0.103810253f);
      const float f1 = exp2f(-(float)(i1 & 127) * 0.103810253f);
      float s0, cc0, s1, cc1;
      sincosf(p * f0, &s0, &cc0);
      sincosf(p * f1, &s1, &cc1);
      outv[e]     = n[e] * cc0 - n[e + 1] * s0;
      outv[e + 1] = n[e + 1] * cc1 + n[e] * s1;
    }
#pragma unroll
    for (int j = 0; j < 4; ++j) base[d0 + j] = (__bf16)outv[j];
  } else {
    __shared__ __bf16 tile[64][72];
    const int b   = blockIdx.x - 12288;       // 0..1023
    const int tid = threadIdx.x;
    const int tb  = (b & 63) * 64;
    const int yy  = b >> 6;                   // 0..15
    const int kvh = yy >> 2;
    const int db  = (yy & 3) * 64;
#pragma unroll
    for (int i = 0; i < 2; ++i) {
      const int s = i * 256 + tid;
      const int r = s >> 3, c = (s & 7) * 8;
      bf16x8 val = *(const bf16x8*)(qkv + (size_t)(tb + r) * 4096 + 3072 + kvh * HD + db + c);
#pragma unroll
      for (int j = 0; j < 8; ++j) tile[r][c + j] = val[j];
    }
    __syncthreads();
#pragma unroll
    for (int i = 0; i < 2; ++i) {
      const int s = i * 256 + tid;
      const int r = s >> 3, c = (s & 7) * 8;
      bf16x8 outv;
#pragma unroll
      for (int j = 0; j < 8; ++j) outv[j] = tile[c + j][r];
      *(bf16x8*)(Vt + (size_t)(kvh * HD + db + r) * SEQ + tb + c) = outv;
    }
  }
}

// ---------------------------------------------------------------------------
// Sliding-window flash attention — round-2 v2 structure (measured 65.9 µs;
// the round-4 "S-next" pipeline regressed and was reverted), plus a
// wave-uniform full-tile fast path in the softmax (skips mask compares on
// ~85% of tiles; qw/kb are wave-uniform so no divergence).
//   - KVBLK=32, K/V double-buffered in LDS (70.7 KB -> 2 blocks/CU).
//   - counted vmcnt(8) gate (never 0 in loop); tile kt's loads issued at the
//     END of body kt-2; tail = clamped dummy re-issues; exit vmcnt(0).
//   - T2 swizzle on K and V; head-per-XCD pinning (K/V L2-resident).
// ---------------------------------------------------------------------------
__global__ __launch_bounds__(256, 2)
void attn_fwd(const __bf16* __restrict__ qkv, const __bf16* __restrict__ Vt,
              __bf16* __restrict__ Y) {
  __shared__ char klds[2][16384];      // [slot][32 key][32 dim] rows of 64B, swz
  __shared__ char vlds[2][16384];      // [slot][256 dim][32 key] rows of 64B, swz
  __shared__ __bf16 Ps[4][16][40];     // per-wave P (padded rows)
  const int tid  = threadIdx.x;
  const int lane = tid & 63;
  const int wave = tid >> 6;
  const int l15  = lane & 15;
  const int l4   = lane >> 4;
  const int lin  = blockIdx.x;
  const int head = lin & 7;            // head-per-XCD pinning
  const int q0   = (lin >> 3) * 64;
  const int kvh  = head >> 1;
  const int qw   = q0 + wave * 16;

  // Q fragments: A[m=lane&15][k=(lane>>4)*8+j]; pre-scale 1/16 (exact pow2)
  bf16x8 qf[8];
  const __bf16* qrow = qkv + (size_t)(qw + l15) * 4096 + head * HD;
#pragma unroll
  for (int ks = 0; ks < 8; ++ks) {
    bf16x8 t = *(const bf16x8*)(qrow + ks * 32 + l4 * 8);
#pragma unroll
    for (int j = 0; j < 8; ++j) t[j] = (__bf16)((float)t[j] * 0.0625f);
    qf[ks] = t;
  }

  f32x4 o[16] = {};
  float l_run[4] = {0.f, 0.f, 0.f, 0.f};

  int lo = q0 - (WIN - 1); if (lo < 0) lo = 0;
  const int kt0 = lo >> 5;
  const int kt1 = (q0 + 63) >> 5;      // >= kt0+1 always (>=2 tiles)
  const int kbmax = kt1 << 5;

  const int skey = (tid >> 2) & 31;                 // K: key row
  const int sdim = tid >> 2;                        // V: dim row (+ i*64)
  const int sg   = (tid & 3) ^ ((tid >> 3) & 3);    // swizzled source col16
  const int sth  = tid >> 7;

  auto stK = [&](int kt, int b) {
    int kb = kt << 5; if (kb > kbmax) kb = kbmax;   // clamped dummy re-issue
    const __bf16* s = qkv + (size_t)(kb + skey) * 4096 + 2048 + kvh * HD
                          + sth * 32 + sg * 8;
    char* d = klds[b] + wave * 1024;
#pragma unroll
    for (int i = 0; i < 4; ++i)
      gload16(s + i * 64, d + i * 4096);
  };
  auto stV = [&](int kt, int b) {
    int kb = kt << 5; if (kb > kbmax) kb = kbmax;
    const __bf16* s = Vt + ((size_t)kvh * HD + sdim) * SEQ + kb + sg * 8;
    char* d = vlds[b] + wave * 1024;
#pragma unroll
    for (int i = 0; i < 4; ++i)
      gload16(s + (size_t)i * 64 * SEQ, d + i * 4096);
  };

  stK(kt0, 0);     stV(kt0, 0);
  stK(kt0 + 1, 1); stV(kt0 + 1, 1);

  const int rswz = (l4 ^ ((l15 >> 1) & 3)) << 4;

  for (int kt = kt0; kt <= kt1; ++kt) {
    const int p  = (kt - kt0) & 1;
    const int kb = kt << 5;
    asm volatile("s_waitcnt vmcnt(8)" ::: "memory");
    barx();

    // S = (Q/16) K^T   (32 keys: kn = 0..1)
    const char* kbase = klds[p];
    f32x4 s_acc[2] = {};
    __builtin_amdgcn_s_setprio(1);
#pragma unroll
    for (int kn = 0; kn < 2; ++kn) {
#pragma unroll
      for (int ks = 0; ks < 8; ++ks) {
        bf16x8 kf = *(const bf16x8*)(kbase + (ks * 32 + kn * 16 + l15) * 64 + rswz);
        s_acc[kn] = __builtin_amdgcn_mfma_f32_16x16x32_bf16(qf[ks], kf, s_acc[kn], 0, 0, 0);
      }
    }
    __builtin_amdgcn_s_setprio(0);

    // fixed-max softmax: p = exp(min(s,34)-34); masked -> 0
    // Fast path (wave-uniform): tile fully inside causal+window for all 16
    // rows of this wave iff kb+31 <= qw  &&  kb >= qw-1008.
    if ((kb + 31 <= qw) && (kb >= qw - 1008)) {
#pragma unroll
      for (int reg = 0; reg < 4; ++reg) {
        const int r = l4 * 4 + reg;
        float ps = 0.f;
#pragma unroll
        for (int kn = 0; kn < 2; ++kn) {
          const float pv = __expf(fminf(s_acc[kn][reg], 34.f) - 34.f);
          ps += pv;
          Ps[wave][r][kn * 16 + l15] = (__bf16)pv;
        }
        l_run[reg] += ps;
      }
    } else {
#pragma unroll
      for (int reg = 0; reg < 4; ++reg) {
        const int r  = l4 * 4 + reg;
        const int qg = qw + r;
        float ps = 0.f;
#pragma unroll
        for (int kn = 0; kn < 2; ++kn) {
          const int kg = kb + kn * 16 + l15;
          const bool ok = (kg <= qg) && (kg > qg - WIN);
          const float pv = ok ? __expf(fminf(s_acc[kn][reg], 34.f) - 34.f) : 0.f;
          ps += pv;
          Ps[wave][r][kn * 16 + l15] = (__bf16)pv;
        }
        l_run[reg] += ps;
      }
    }

    // O += P V   (Ps per-wave; intra-wave LDS ordering needs no barrier)
    const char* vbase = vlds[p];
    bf16x8 pf = *(const bf16x8*)&Ps[wave][l15][l4 * 8];
    __builtin_amdgcn_s_setprio(1);
#pragma unroll
    for (int dn = 0; dn < 16; ++dn) {
      bf16x8 vf = *(const bf16x8*)(vbase + (dn * 16 + l15) * 64 + rswz);
      o[dn] = __builtin_amdgcn_mfma_f32_16x16x32_bf16(pf, vf, o[dn], 0, 0, 0);
    }
    __builtin_amdgcn_s_setprio(0);

    // retire buf p readers, then refill it with tile kt+2
    barx();
    stK(kt + 2, p);
    stV(kt + 2, p);
  }
  // no DMA in flight at exit (LDS may be reassigned to the next block)
  asm volatile("s_waitcnt vmcnt(0)" ::: "memory");

  // epilogue: reduce l across the 16 lanes sharing each row, then scale
#pragma unroll
  for (int reg = 0; reg < 4; ++reg) {
#pragma unroll
    for (int off = 1; off < 16; off <<= 1)
      l_run[reg] += __shfl_xor(l_run[reg], off);
    const float inv = 1.0f / l_run[reg];
    const int q = qw + l4 * 4 + reg;
    __bf16* yrow = Y + ((size_t)q * NH + head) * HD + l15;
#pragma unroll
    for (int dn = 0; dn < 16; ++dn)
      yrow[dn * 16] = (__bf16)(o[dn][reg] * inv);
  }
}

// ---------------------------------------------------------------------------
extern "C" void kernel_launch(void* const* d_in, const int* in_sizes, int n_in,
                              void* d_out, int out_size, void* d_ws, size_t ws_size,
                              hipStream_t stream) {
  (void)in_sizes; (void)n_in; (void)out_size; (void)ws_size;
  const float* x   = (const float*)d_in[0];
  const int*   pos = (const int*)d_in[1];
  const float* Wq  = (const float*)d_in[2];
  const float* Wk  = (const float*)d_in[3];
  const float* Wv  = (const float*)d_in[4];
  const float* Wo  = (const float*)d_in[5];
  const float* qw  = (const float*)d_in[6];
  const float* kw  = (const float*)d_in[7];
  float* out = (float*)d_out;

  char* ws = (char*)d_ws;
  const size_t MB = 1024 * 1024;
  __bf16* qkv_ws = (__bf16*)(ws);             // 32 MiB  [4096][4096]
  __bf16* vt_ws  = (__bf16*)(ws + 32 * MB);   //  8 MiB  [4][256][4096]
  __bf16* y_ws   = (__bf16*)(ws + 40 * MB);   // 16 MiB  [4096][2048]
  __bf16* xb     = (__bf16*)(ws + 56 * MB);   // 16 MiB
  __bf16* wqkvb  = (__bf16*)(ws + 72 * MB);   // 16 MiB  [4096][2048]
  __bf16* wob    = (__bf16*)(ws + 88 * MB);   //  8 MiB  (total 96 MiB)

  cvt_all<<<dim3(10240), dim3(256), 0, stream>>>(x, Wq, Wk, Wv, Wo, xb, wqkvb, wob);
  gemm256<256, __bf16><<<dim3(256), dim3(512), 0, stream>>>(xb, wqkvb, qkv_ws, 4096, 2048);
  norm_rope_tv<<<dim3(13312), dim3(256), 0, stream>>>(qkv_ws, vt_ws, qw, kw, pos);
  attn_fwd<<<dim3(512), dim3(256), 0, stream>>>(qkv_ws, vt_ws, y_ws);
  gemm2ph<128, float><<<dim3(256), dim3(512), 0, stream>>>(y_ws, wob, out, 2048, 2048);
}